// Round 1
// baseline (10001.515 us; speedup 1.0000x reference)
//
#include <hip/hip_runtime.h>
#include <math.h>

#define LNUM 2
#define H 24
#define KVH 8
#define GQ 3
#define D 128
#define ROT 96
#define HALF 48
#define HID 3072
#define FF 8192
#define V 32000
#define S 1024
#define QP (H*D)              // 3072
#define KP (KVH*D)            // 1024
#define QKV_OUT (QP + 2*KP)   // 5120
#define EPSI 1e-6f
#define SCALE 0.29730177875068026f  // 128^-0.25

// ---------------- embed: h[s][c] = (float)eq[id][c]*scale[id] + zero[id] ----------------
__global__ __launch_bounds__(256) void embed_kernel(const int* __restrict__ ids,
    const int* __restrict__ eq, const float* __restrict__ esc,
    const float* __restrict__ ezr, float* __restrict__ h) {
  int s = blockIdx.x;
  int id = ids[s];
  const int* row = eq + (long)id * HID;
  float sc = esc[id], zr = ezr[id];
  for (int c = threadIdx.x; c < HID; c += 256)
    h[(long)s*HID + c] = (float)row[c] * sc + zr;
}

// ---------------- rmsnorm per row ----------------
__global__ __launch_bounds__(256) void rmsnorm_kernel(const float* __restrict__ x,
    const float* __restrict__ w, float* __restrict__ y) {
  int s = blockIdx.x;
  const float* xr = x + (long)s*HID;
  float ss = 0.f;
  for (int c = threadIdx.x; c < HID; c += 256) { float v = xr[c]; ss += v*v; }
  #pragma unroll
  for (int off = 32; off > 0; off >>= 1) ss += __shfl_xor(ss, off, 64);
  __shared__ float red[4];
  int wid = threadIdx.x >> 6;
  if ((threadIdx.x & 63) == 0) red[wid] = ss;
  __syncthreads();
  float tot = red[0] + red[1] + red[2] + red[3];
  float inv = rsqrtf(tot / (float)HID + EPSI);
  for (int c = threadIdx.x; c < HID; c += 256)
    y[(long)s*HID + c] = xr[c] * inv * w[c];
}

// ---------------- fp32 GEMM: C[M x N] = (RESID? Rsrc:0) + A[M x K] * W[N x K]^T ----------------
#define BM 128
#define BN 128
#define BK 32

template<bool RESID>
__global__ __launch_bounds__(256) void gemm_kernel(const float* __restrict__ A,
    const float* __restrict__ W, const float* __restrict__ Rsrc, float* __restrict__ C,
    int N, int K) {
  __shared__ float As[BK][BM+4];
  __shared__ float Ws[BK][BN+4];
  const int row0 = blockIdx.x * BM;
  const int col0 = blockIdx.y * BN;
  const int tid = threadIdx.x;
  const int ty = tid >> 4, tx = tid & 15;  // owns rows ty*8..+7, cols tx*8..+7
  float acc[8][8];
  #pragma unroll
  for (int i = 0; i < 8; i++)
    #pragma unroll
    for (int j = 0; j < 8; j++) acc[i][j] = 0.f;

  for (int k0 = 0; k0 < K; k0 += BK) {
    #pragma unroll
    for (int i = 0; i < 4; i++) {
      int idx = tid + i*256;            // 0..1023
      int m = idx >> 3, kq = idx & 7;   // m 0..127, kq 0..7 (k = kq*4)
      float4 v = *(const float4*)(A + (long)(row0+m)*K + k0 + kq*4);
      As[kq*4+0][m] = v.x; As[kq*4+1][m] = v.y; As[kq*4+2][m] = v.z; As[kq*4+3][m] = v.w;
      float4 u = *(const float4*)(W + (long)(col0+m)*K + k0 + kq*4);
      Ws[kq*4+0][m] = u.x; Ws[kq*4+1][m] = u.y; Ws[kq*4+2][m] = u.z; Ws[kq*4+3][m] = u.w;
    }
    __syncthreads();
    #pragma unroll 8
    for (int kk = 0; kk < BK; kk++) {
      float a[8], b[8];
      *(float4*)&a[0] = *(const float4*)&As[kk][ty*8];
      *(float4*)&a[4] = *(const float4*)&As[kk][ty*8+4];
      *(float4*)&b[0] = *(const float4*)&Ws[kk][tx*8];
      *(float4*)&b[4] = *(const float4*)&Ws[kk][tx*8+4];
      #pragma unroll
      for (int i = 0; i < 8; i++)
        #pragma unroll
        for (int j = 0; j < 8; j++) acc[i][j] = fmaf(a[i], b[j], acc[i][j]);
    }
    __syncthreads();
  }
  #pragma unroll
  for (int i = 0; i < 8; i++) {
    long r = row0 + ty*8 + i;
    float* crow = C + r*(long)N + col0 + tx*8;
    float4 o0 = make_float4(acc[i][0], acc[i][1], acc[i][2], acc[i][3]);
    float4 o1 = make_float4(acc[i][4], acc[i][5], acc[i][6], acc[i][7]);
    if (RESID) {
      const float* rrow = Rsrc + r*(long)N + col0 + tx*8;
      float4 r0 = *(const float4*)(rrow);
      float4 r1 = *(const float4*)(rrow+4);
      o0.x += r0.x; o0.y += r0.y; o0.z += r0.z; o0.w += r0.w;
      o1.x += r1.x; o1.y += r1.y; o1.z += r1.z; o1.w += r1.w;
    }
    *(float4*)(crow) = o0;
    *(float4*)(crow+4) = o1;
  }
}

// ---------------- rope + scatter: qkv row -> qrot [H][S][D], keys [KV][D][S], vals [KV][S][D] ----------------
__global__ __launch_bounds__(256) void rope_kernel(const float* __restrict__ qkvb,
    const float* __restrict__ cosE, const float* __restrict__ sinE,
    float* __restrict__ qrot, float* __restrict__ keysL, float* __restrict__ valsL) {
  int s = blockIdx.x;
  const float* row = qkvb + (long)s * QKV_OUT;
  for (int c = threadIdx.x; c < QKV_OUT; c += 256) {
    if (c < QP) {
      int hh = c >> 7, d = c & 127;
      float v = row[c] * SCALE;
      float outv;
      if (d < ROT) {
        float cs = cosE[s*ROT + d], sn = sinE[s*ROT + d];
        int pd = (d < HALF) ? (d + HALF) : (d - HALF);
        float partner = row[(c & ~127) | pd] * SCALE;
        outv = v*cs + ((d < HALF) ? -partner : partner) * sn;
      } else outv = v;
      qrot[((long)hh*S + s)*D + d] = outv;
    } else if (c < QP + KP) {
      int cc = c - QP;
      int kvh = cc >> 7, d = cc & 127;
      float v = row[c] * SCALE;
      float outv;
      if (d < ROT) {
        float cs = cosE[s*ROT + d], sn = sinE[s*ROT + d];
        int pd = (d < HALF) ? (d + HALF) : (d - HALF);
        float partner = row[QP + ((cc & ~127) | pd)] * SCALE;
        outv = v*cs + ((d < HALF) ? -partner : partner) * sn;
      } else outv = v;
      keysL[((long)kvh*D + d)*S + s] = outv;
    } else {
      int cc = c - QP - KP;
      int kvh = cc >> 7, d = cc & 127;
      valsL[((long)kvh*S + s)*D + d] = row[c];
    }
  }
}

// ---------------- flash attention fp32: per block (head, 32 q-rows) ----------------
#define ABM 32
#define ABN 32

__global__ __launch_bounds__(256) void attn_kernel(const float* __restrict__ qb,
    const float* __restrict__ Kg, const float* __restrict__ Vg,
    const int* __restrict__ maskp, float* __restrict__ ao) {
  int hq = blockIdx.y;
  int s0 = blockIdx.x * ABM;
  int kv = hq / GQ;
  __shared__ float Qs[ABM][D+4];
  __shared__ float Kc[D][ABN];
  __shared__ float Vc[ABN][D+4];
  __shared__ float Ps[ABM][ABN+4];
  int tid = threadIdx.x;
  int srow = tid >> 3, tq = tid & 7;
  int mflag = *maskp;
  float maskf = (float)mflag;
  int t_max = mflag ? (s0 + ABM) : S;   // fully-masked chunks contribute exactly 0 in fp32

  #pragma unroll
  for (int i = 0; i < 4; i++) {
    int idx = tid + i*256; int s = idx >> 5, d4 = idx & 31;
    *(float4*)&Qs[s][d4*4] = *(const float4*)(qb + ((long)hq*S + s0 + s)*D + d4*4);
  }
  float m_r = -1e30f, l_r = 0.f;
  float acc[16];
  #pragma unroll
  for (int i = 0; i < 16; i++) acc[i] = 0.f;

  for (int t0 = 0; t0 < t_max; t0 += ABN) {
    __syncthreads();  // protect LDS from previous iter's readers
    #pragma unroll
    for (int i = 0; i < 4; i++) {
      int idx = tid + i*256;            // 0..1023
      int d = idx >> 3, tg = idx & 7;
      *(float4*)&Kc[d][tg*4] = *(const float4*)(Kg + ((long)kv*D + d)*S + t0 + tg*4);
      int t = idx >> 5, d4 = idx & 31;
      *(float4*)&Vc[t][d4*4] = *(const float4*)(Vg + ((long)kv*S + t0 + t)*D + d4*4);
    }
    __syncthreads();
    float sc0=0.f, sc1=0.f, sc2=0.f, sc3=0.f;
    for (int d = 0; d < D; d++) {
      float qv = Qs[srow][d];
      float4 kk = *(const float4*)&Kc[d][tq*4];
      sc0 = fmaf(qv, kk.x, sc0); sc1 = fmaf(qv, kk.y, sc1);
      sc2 = fmaf(qv, kk.z, sc2); sc3 = fmaf(qv, kk.w, sc3);
    }
    int sg = s0 + srow;
    int tg0 = t0 + tq*4;
    if (tg0+0 > sg) sc0 -= 128.f*maskf;
    if (tg0+1 > sg) sc1 -= 128.f*maskf;
    if (tg0+2 > sg) sc2 -= 128.f*maskf;
    if (tg0+3 > sg) sc3 -= 128.f*maskf;
    float mx = fmaxf(fmaxf(sc0, sc1), fmaxf(sc2, sc3));
    mx = fmaxf(mx, __shfl_xor(mx, 1, 8));
    mx = fmaxf(mx, __shfl_xor(mx, 2, 8));
    mx = fmaxf(mx, __shfl_xor(mx, 4, 8));
    float m_new = fmaxf(m_r, mx);
    float p0 = __expf(sc0 - m_new), p1 = __expf(sc1 - m_new);
    float p2 = __expf(sc2 - m_new), p3 = __expf(sc3 - m_new);
    float ps = p0 + p1 + p2 + p3;
    ps += __shfl_xor(ps, 1, 8); ps += __shfl_xor(ps, 2, 8); ps += __shfl_xor(ps, 4, 8);
    float alpha = __expf(m_r - m_new);
    l_r = l_r * alpha + ps;
    m_r = m_new;
    *(float4*)&Ps[srow][tq*4] = make_float4(p0, p1, p2, p3);
    #pragma unroll
    for (int i = 0; i < 16; i++) acc[i] *= alpha;
    __syncthreads();
    for (int t = 0; t < ABN; t++) {
      float pv = Ps[srow][t];
      #pragma unroll
      for (int k = 0; k < 4; k++) {
        float4 vv = *(const float4*)&Vc[t][k*32 + tq*4];
        acc[k*4+0] = fmaf(pv, vv.x, acc[k*4+0]);
        acc[k*4+1] = fmaf(pv, vv.y, acc[k*4+1]);
        acc[k*4+2] = fmaf(pv, vv.z, acc[k*4+2]);
        acc[k*4+3] = fmaf(pv, vv.w, acc[k*4+3]);
      }
    }
  }
  float inv = 1.f / l_r;
  #pragma unroll
  for (int k = 0; k < 4; k++) {
    float4 o = make_float4(acc[k*4]*inv, acc[k*4+1]*inv, acc[k*4+2]*inv, acc[k*4+3]*inv);
    *(float4*)(ao + (long)(s0+srow)*(H*D) + hq*D + k*32 + tq*4) = o;
  }
}

// ---------------- silu(gate)*up ----------------
__global__ __launch_bounds__(256) void silu_mul_kernel(const float* __restrict__ gu,
                                                       float* __restrict__ act) {
  long i4 = (long)blockIdx.x * 256 + threadIdx.x;   // 0 .. S*FF/4-1
  long s = i4 / (FF/4), f4 = i4 % (FF/4);
  const float* base = gu + s*(2L*FF);
  float4 g = *(const float4*)(base + f4*4);
  float4 u = *(const float4*)(base + FF + f4*4);
  float4 o;
  o.x = g.x / (1.f + __expf(-g.x)) * u.x;
  o.y = g.y / (1.f + __expf(-g.y)) * u.y;
  o.z = g.z / (1.f + __expf(-g.z)) * u.z;
  o.w = g.w / (1.f + __expf(-g.w)) * u.w;
  *(float4*)(act + s*(long)FF + f4*4) = o;
}

// ---------------- final rms of last row ----------------
__global__ __launch_bounds__(256) void final_rms_kernel(const float* __restrict__ h,
    const float* __restrict__ w, float* __restrict__ hl) {
  const float* xr = h + (long)(S-1)*HID;
  float ss = 0.f;
  for (int c = threadIdx.x; c < HID; c += 256) { float v = xr[c]; ss += v*v; }
  #pragma unroll
  for (int off = 32; off > 0; off >>= 1) ss += __shfl_xor(ss, off, 64);
  __shared__ float red[4];
  int wid = threadIdx.x >> 6;
  if ((threadIdx.x & 63) == 0) red[wid] = ss;
  __syncthreads();
  float tot = red[0] + red[1] + red[2] + red[3];
  float inv = rsqrtf(tot / (float)HID + EPSI);
  for (int c = threadIdx.x; c < HID; c += 256) hl[c] = xr[c] * inv * w[c];
}

// ---------------- lm head gemv: 4 rows/block, one wave per row ----------------
__global__ __launch_bounds__(256) void gemv_kernel(const float* __restrict__ hl,
    const float* __restrict__ Wv, float* __restrict__ logits) {
  int row = blockIdx.x * 4 + (threadIdx.x >> 6);
  int lane = threadIdx.x & 63;
  const float4* wr = (const float4*)(Wv + (long)row*HID);
  const float4* hr = (const float4*)hl;
  float ssum = 0.f;
  for (int i = lane; i < HID/4; i += 64) {
    float4 a = wr[i], b = hr[i];
    ssum += a.x*b.x + a.y*b.y + a.z*b.z + a.w*b.w;
  }
  #pragma unroll
  for (int off = 32; off > 0; off >>= 1) ssum += __shfl_xor(ssum, off, 64);
  if (lane == 0) logits[row] = ssum;
}

// ---------------- argmax + scalar outputs ----------------
__global__ __launch_bounds__(256) void argmax_kernel(const float* __restrict__ logits,
                                                     float* __restrict__ outsc) {
  __shared__ float vals[256];
  __shared__ int idxs[256];
  int tid = threadIdx.x;
  float best = -1e30f; int bi = 0;
  for (int i = tid; i < V; i += 256) {
    float v = logits[i];
    if (v > best) { best = v; bi = i; }
  }
  vals[tid] = best; idxs[tid] = bi;
  __syncthreads();
  for (int st = 128; st > 0; st >>= 1) {
    if (tid < st) {
      if (vals[tid+st] > vals[tid] || (vals[tid+st] == vals[tid] && idxs[tid+st] < idxs[tid])) {
        vals[tid] = vals[tid+st]; idxs[tid] = idxs[tid+st];
      }
    }
    __syncthreads();
  }
  if (tid == 0) {
    outsc[0] = 1024.0f;            // kv_seq_len = S
    outsc[1] = (float)idxs[0];     // token
  }
}

extern "C" void kernel_launch(void* const* d_in, const int* in_sizes, int n_in,
                              void* d_out, int out_size, void* d_ws, size_t ws_size,
                              hipStream_t stream) {
  const int*   ids  = (const int*)d_in[0];
  const int*   mfp  = (const int*)d_in[1];
  const int*   eq   = (const int*)d_in[2];
  const float* esc  = (const float*)d_in[3];
  const float* ezr  = (const float*)d_in[4];
  const float* ln1  = (const float*)d_in[5];
  const float* qkvw = (const float*)d_in[6];
  const float* ow   = (const float*)d_in[7];
  const float* ln2  = (const float*)d_in[8];
  const float* guw  = (const float*)d_in[9];
  const float* dww  = (const float*)d_in[10];
  const float* nw   = (const float*)d_in[11];
  const float* lmw  = (const float*)d_in[12];
  const float* cosE = (const float*)d_in[13];
  const float* sinE = (const float*)d_in[14];
  float* out = (float*)d_out;

  float* ws   = (float*)d_ws;
  float* h    = ws;                    // S*HID
  float* hn   = ws + 3145728L;         // S*HID
  float* R    = ws + 6291456L;         // reused region (25,165,824 floats)
  float* qkvb = R;                     // S*5120
  float* qrot = R + 5242880L;          // H*S*D
  float* ao   = R + 8388608L;          // S*HID
  float* gu   = R;                     // S*2FF   (aliases qkvb/qrot/ao - dead by then)
  float* act  = R + 16777216L;         // S*FF
  float* hl   = ws + 31457280L;        // HID
  float* logits = ws + 31460352L;      // V

  float* keys0 = out;                  // [L][KV][D][S]
  float* vals0 = out + 2097152L;       // [L][KV][S][D]
  float* outsc = out + 4194304L;       // kv_seq_len, token

  embed_kernel<<<S, 256, 0, stream>>>(ids, eq, esc, ezr, h);

  for (int l = 0; l < LNUM; l++) {
    const float* qw  = qkvw + (long)l * QKV_OUT * HID;
    const float* owl = ow   + (long)l * HID * QP;
    const float* gwl = guw  + (long)l * 2L * FF * HID;
    const float* dwl = dww  + (long)l * HID * FF;
    float* keysL = keys0 + (long)l * KVH * D * S;
    float* valsL = vals0 + (long)l * KVH * S * D;

    rmsnorm_kernel<<<S, 256, 0, stream>>>(h, ln1 + (long)l*HID, hn);
    gemm_kernel<false><<<dim3(S/BM, QKV_OUT/BN), 256, 0, stream>>>(hn, qw, nullptr, qkvb, QKV_OUT, HID);
    rope_kernel<<<S, 256, 0, stream>>>(qkvb, cosE, sinE, qrot, keysL, valsL);
    attn_kernel<<<dim3(S/ABM, H), 256, 0, stream>>>(qrot, keysL, valsL, mfp, ao);
    gemm_kernel<true><<<dim3(S/BM, HID/BN), 256, 0, stream>>>(ao, owl, h, h, HID, QP);
    rmsnorm_kernel<<<S, 256, 0, stream>>>(h, ln2 + (long)l*HID, hn);
    gemm_kernel<false><<<dim3(S/BM, 2*FF/BN), 256, 0, stream>>>(hn, gwl, nullptr, gu, 2*FF, HID);
    silu_mul_kernel<<<S*FF/4/256, 256, 0, stream>>>(gu, act);
    gemm_kernel<true><<<dim3(S/BM, HID/BN), 256, 0, stream>>>(act, dwl, h, h, HID, FF);
  }

  final_rms_kernel<<<1, 256, 0, stream>>>(h, nw, hl);
  gemv_kernel<<<V/4, 256, 0, stream>>>(hl, lmw, logits);
  argmax_kernel<<<1, 256, 0, stream>>>(logits, outsc);
}